// Round 5
// baseline (168.674 us; speedup 1.0000x reference)
//
#include <hip/hip_runtime.h>
#include <hip/hip_bf16.h>
#include <math.h>

#define B_  16
#define C_  64
#define HW_ 128
#define E_  8
#define GH_ 16

typedef __attribute__((ext_vector_type(8))) short short8;
typedef __attribute__((ext_vector_type(4))) short short4v;
typedef __attribute__((ext_vector_type(4))) float float4v;

// per-sample packed weights: [9 pos][2 khalf][4 quad][64 co][8 ci] bf16
#define WB_PER_B (9 * 2 * 4 * 64 * 8)     // 36864

// ---- workspace layout (bytes) ----
#define WS_WB_OFF     0
#define WS_WB_BYTES   (B_ * WB_PER_B * 2)               // 1,179,648
#define WS_BCOMB_OFF  (WS_WB_OFF + WS_WB_BYTES)
#define WS_BCOMB_BYTES (B_ * C_ * 4)                    // 4096
#define WS_PP_OFF     (WS_BCOMB_OFF + WS_BCOMB_BYTES)
#define WS_PP_BYTES   (B_ * C_ * 64 * 4)                // 262,144 (pool partials [b][c][rb])
#define WS_XP_OFF     (WS_PP_OFF + WS_PP_BYTES)         // 16B aligned
#define WS_XP_BYTES   ((size_t)B_ * HW_ * HW_ * C_ * 2) // 33,554,432 (bf16 NHWC swizzled)
#define WS_NEED       ((size_t)WS_XP_OFF + WS_XP_BYTES)

// fallback (old conv) tiling constants
#define ROWS_LDS 4
#define COLS_LDS 132
#define XS_SHORTS (ROWS_LDS * COLS_LDS * 32)

// v4 conv LDS: [4 rows][66 cols][4 slots][8 ci] bf16 per buffer, dbuf
#define COLS_T 66
#define BUFT_SHORTS (4 * COLS_T * 32)     // 8448 shorts = 16896 B

// ---------------------------------------------------------------------------
// K1: fused transpose + pool (R3 layout: per-column-quad ci-group swizzle
// only).  Reads x [b][c][h][w] f32; writes xp [b][h][w][64] bf16 where
// within each 32-ci half, group slot p at column w holds ci-group
// (p ^ ((w>>2)&3)).  Also writes per-(b,c) row-block partial sums
// pp[b][c][rb] (rb = 2-row block, 64 per image) for the gate pool.
// ---------------------------------------------------------------------------
__global__ __launch_bounds__(256) void transpose_pool_kernel(
    const float* __restrict__ x, __hip_bfloat16* __restrict__ xp,
    float* __restrict__ pp) {
  __shared__ float pred[256 * 4];
  const int t = threadIdx.x;
  const int b = blockIdx.x >> 6;
  const int rb = blockIdx.x & 63;
  const int cg = t & 15;        // channel-quad (4 ch each)
  const int cq = t >> 4;        // col-quad index within half-row
  const int g = cg >> 1;        // 8-ci group 0..7
  const int kh = g >> 2;        // ci half
  const int g_lo = g & 3;
  const int h4 = cg & 1;        // which 4 of the 8-group

  float s0 = 0.f, s1 = 0.f, s2 = 0.f, s3 = 0.f;

  for (int rr = 0; rr < 2; rr++) {
    const int r = rb * 2 + rr;
    const float* xr = x + ((size_t)b * C_ * HW_ + (size_t)r) * HW_;
    __hip_bfloat16* xpr = xp + ((size_t)(b * HW_ + r) * HW_) * C_;
#pragma unroll
    for (int ih = 0; ih < 2; ih++) {
      const int w4 = ih * 16 + cq;    // 0..31
      float4v v0 = *(const float4v*)(xr + (size_t)(cg * 4 + 0) * (HW_ * HW_) + w4 * 4);
      float4v v1 = *(const float4v*)(xr + (size_t)(cg * 4 + 1) * (HW_ * HW_) + w4 * 4);
      float4v v2 = *(const float4v*)(xr + (size_t)(cg * 4 + 2) * (HW_ * HW_) + w4 * 4);
      float4v v3 = *(const float4v*)(xr + (size_t)(cg * 4 + 3) * (HW_ * HW_) + w4 * 4);
      s0 += (v0.x + v0.y) + (v0.z + v0.w);
      s1 += (v1.x + v1.y) + (v1.z + v1.w);
      s2 += (v2.x + v2.y) + (v2.z + v2.w);
      s3 += (v3.x + v3.y) + (v3.z + v3.w);
      const int pos_lo = g_lo ^ (w4 & 3);
      const int coff = kh * 32 + pos_lo * 8 + h4 * 4;
#pragma unroll
      for (int j = 0; j < 4; j++) {
        const int w = w4 * 4 + j;
        __hip_bfloat16 b0 = __float2bfloat16(v0[j]);
        __hip_bfloat16 b1 = __float2bfloat16(v1[j]);
        __hip_bfloat16 b2 = __float2bfloat16(v2[j]);
        __hip_bfloat16 b3 = __float2bfloat16(v3[j]);
        short4v pk;
        pk[0] = *(short*)&b0;
        pk[1] = *(short*)&b1;
        pk[2] = *(short*)&b2;
        pk[3] = *(short*)&b3;
        *(short4v*)(xpr + (size_t)w * C_ + coff) = pk;
      }
    }
  }
  pred[t * 4 + 0] = s0;
  pred[t * 4 + 1] = s1;
  pred[t * 4 + 2] = s2;
  pred[t * 4 + 3] = s3;
  __syncthreads();
  if (t < C_) {
    const int kk = t & 3, cgr = t >> 2;
    float a = 0.f;
#pragma unroll
    for (int m = 0; m < 16; m++) a += pred[(cgr + 16 * m) * 4 + kk];
    pp[((size_t)b * C_ + t) * 64 + rb] = a;
  }
}

// ---------------------------------------------------------------------------
// K1 (fallback): plain global average pool.
// ---------------------------------------------------------------------------
__global__ __launch_bounds__(256) void pool_kernel(const float* __restrict__ x,
                                                   float* __restrict__ pooled) {
  const int bc = blockIdx.x;
  const float4v* p4 = (const float4v*)(x + (size_t)bc * (HW_ * HW_));
  float4v s4 = {0.f, 0.f, 0.f, 0.f};
  for (int i = threadIdx.x; i < (HW_ * HW_) / 4; i += 256) s4 += p4[i];
  float s = (s4.x + s4.y) + (s4.z + s4.w);
#pragma unroll
  for (int off = 32; off > 0; off >>= 1) s += __shfl_down(s, off, 64);
  __shared__ float red[4];
  if ((threadIdx.x & 63) == 0) red[threadIdx.x >> 6] = s;
  __syncthreads();
  if (threadIdx.x == 0)
    pooled[bc] = (red[0] + red[1] + red[2] + red[3]) * (1.0f / (HW_ * HW_));
}

// ---------------------------------------------------------------------------
// K2: fused gate + weight combine into packed bf16 B-fragment layout, with
// the residual identity folded into the center tap.  Grid = B_*16 (4 co per
// block; 256 blocks = 1/CU).  use_pp=1: pooled means from pp partials.
// ---------------------------------------------------------------------------
__global__ __launch_bounds__(256) void combine_kernel(
    const float* __restrict__ w_exp, const float* __restrict__ pooled,
    const float* __restrict__ pp, const int use_pp,
    const float* __restrict__ wg1, const float* __restrict__ bg1,
    const float* __restrict__ wg2, const float* __restrict__ bg2,
    const float* __restrict__ b_exp, __hip_bfloat16* __restrict__ wB,
    float* __restrict__ bcomb) {
  __shared__ float wtmp[4 * 576];
  __shared__ float hsh[GH_];
  __shared__ float psh[E_];
  __shared__ float pool_sh[C_];
  const int t = threadIdx.x;
  const int b = blockIdx.x >> 4;
  const int cog = blockIdx.x & 15;

  if (use_pp) {
    if (t < C_) {
      const float4v* pr = (const float4v*)(pp + ((size_t)b * C_ + t) * 64);
      float4v s4 = {0.f, 0.f, 0.f, 0.f};
#pragma unroll
      for (int m = 0; m < 16; m++) s4 += pr[m];
      pool_sh[t] = ((s4.x + s4.y) + (s4.z + s4.w)) * (1.0f / (HW_ * HW_));
    }
  } else {
    if (t < C_) pool_sh[t] = pooled[b * C_ + t];
  }
  __syncthreads();

  if (t < GH_) {
    float s = bg1[t];
    for (int c = 0; c < C_; c++)
      s = fmaf(pool_sh[c], wg1[c * GH_ + t], s);
    hsh[t] = fmaxf(s, 0.f);
  }
  __syncthreads();
  if (t == 0) {
    float p[E_];
    float mx = -1e30f;
#pragma unroll
    for (int e = 0; e < E_; e++) {
      float s = bg2[e];
#pragma unroll
      for (int g = 0; g < GH_; g++) s = fmaf(hsh[g], wg2[g * E_ + e], s);
      p[e] = s;
      mx = fmaxf(mx, s);
    }
    float sum = 0.f;
#pragma unroll
    for (int e = 0; e < E_; e++) { p[e] = expf(p[e] - mx); sum += p[e]; }
    const float inv = 1.0f / sum;
#pragma unroll
    for (int e = 0; e < E_; e++) p[e] *= inv;
    int i1 = 0;
#pragma unroll
    for (int e = 1; e < E_; e++) if (p[e] > p[i1]) i1 = e;
    int i2 = -1;
#pragma unroll
    for (int e = 0; e < E_; e++) {
      if (e == i1) continue;
      if (i2 < 0 || p[e] > p[i2]) i2 = e;
    }
    const float denom = p[i1] + p[i2] + 1e-8f;
#pragma unroll
    for (int e = 0; e < E_; e++)
      psh[e] = (e == i1 || e == i2) ? (p[e] / denom) : 0.f;
  }
  __syncthreads();
  float pb[E_];
#pragma unroll
  for (int e = 0; e < E_; e++) pb[e] = psh[e];

  const size_t src0 = (size_t)cog * 4 * 576;
  for (int i = t; i < 2304; i += 256) {
    float s = 0.f;
#pragma unroll
    for (int e = 0; e < E_; e++)
      s = fmaf(pb[e], w_exp[(size_t)e * (C_ * 576) + src0 + i], s);
    wtmp[i] = s;
  }
  __syncthreads();
  for (int i = t; i < 2304; i += 256) {
    const int j = i & 7;
    const int co_l = (i >> 3) & 3;
    const int rest = i >> 5;
    const int quad = rest & 3;
    const int khalf = (rest >> 2) & 1;
    const int pos = rest >> 3;
    const int ci = khalf * 32 + quad * 8 + j;
    const int co = cog * 4 + co_l;
    float v = wtmp[co_l * 576 + ci * 9 + pos];
    if (pos == 4 && co == ci) v += 1.0f;   // fold residual into conv
    wB[(size_t)b * WB_PER_B +
       ((((pos * 2 + khalf) * 4 + quad) * 64) + co) * 8 + j] =
        __float2bfloat16(v);
  }
  if (t < 4) {
    const int co = cog * 4 + t;
    float s = 0.f;
#pragma unroll
    for (int e = 0; e < E_; e++) s = fmaf(pb[e], b_exp[e * C_ + co], s);
    bcomb[b * C_ + co] = s;
  }
}

__device__ __forceinline__ float4v shx1(float4v v) {
  float4v r;
  r.x = __shfl_xor(v.x, 1, 64);
  r.y = __shfl_xor(v.y, 1, 64);
  r.z = __shfl_xor(v.z, 1, 64);
  r.w = __shfl_xor(v.w, 1, 64);
  return r;
}

// ---------------------------------------------------------------------------
// K3 (v4b): implicit-GEMM conv from bf16 NHWC-swizzled xp.
// Tile = 2 rows x 64 cols (M=128); grid 2048; dbuf LDS = 2 x 16,896 B =
// 33,792 B -> 4 blocks/CU with the double-buffered pipeline (stage kh+1
// issued under compute kh).  Wave layout 2M x 2N.  Resident window = one
// sample per XCD.  New in v4b: kh=0's first B-frag is loaded BEFORE the
// first barrier (flies with stage-0) and kh=1's first B-frag is prefetched
// during kh=0's last MFMA step via a persistent dbuf toggle -> no exposed
// L2 round-trip at either phase start.
// ---------------------------------------------------------------------------
__global__ __launch_bounds__(256, 4) void conv_kernel_v4(
    const __hip_bfloat16* __restrict__ xp, const __hip_bfloat16* __restrict__ wB,
    const float* __restrict__ bcomb, float* __restrict__ out) {
  __shared__ __align__(16) short xs[2][BUFT_SHORTS];

  const int t = threadIdx.x;
  const int blk = blockIdx.x;
  const int xcd = blk & 7;
  const int idx = blk >> 3;               // 0..255
  const int b = xcd * 2 + (idx >> 7);
  const int tile = idx & 127;             // 64 strips x 2 col-halves
  const int ty = (tile >> 1) * 2;
  const int cx = (tile & 1) * 64;

  const int wave = t >> 6;
  const int L = t & 63;
  const int n16 = L & 15;
  const int quad = L >> 4;
  const int wr = wave >> 1;               // row-half 0..1
  const int wc = wave & 1;                // co-half 0..1

  // stage ci-half khs into buffer buf: 1024 interior 16-B chunks (4/thread)
  // + 32 edge chunks (reg->LDS).
  auto stage = [&](int khs, int buf) {
#pragma unroll
    for (int it = 0; it < 4; it++) {
      const int i = it * 256 + t;
      const int slot = i & 3;             // 16-B chunk within 64-B pixel-half
      const int pix = i >> 2;             // 0..255
      const int lw = pix & 63;            // local col
      const int r = pix >> 6;             // 0..3, wave-uniform
      const int gh = ty + r - 1;
      short* dst = &xs[buf][((r * COLS_T + lw + 1) * 4 + slot) * 8];
      if ((unsigned)gh < (unsigned)HW_) {
        const __hip_bfloat16* src =
            xp + ((size_t)(b * HW_ + gh) * HW_ + (cx + lw)) * C_ + khs * 32 +
            slot * 8;
        __builtin_amdgcn_global_load_lds(
            (const __attribute__((address_space(1))) void*)src,
            (__attribute__((address_space(3))) void*)dst, 16, 0, 0);
      } else {
        *(short8*)dst = (short8)0;
      }
    }
    if (t < 32) {
      const int r = t >> 3;
      const int edge = (t >> 2) & 1;
      const int slot = t & 3;
      const int cl = edge ? (COLS_T - 1) : 0;
      const int w = cx + (edge ? 64 : -1);
      const int gh = ty + r - 1;
      short8 v = (short8)0;
      if ((unsigned)gh < (unsigned)HW_ && (unsigned)w < (unsigned)HW_)
        v = *(const short8*)(xp + ((size_t)(b * HW_ + gh) * HW_ + w) * C_ +
                             khs * 32 + slot * 8);
      *(short8*)&xs[buf][((r * COLS_T + cl) * 4 + slot) * 8] = v;
    }
  };

  // persistent B-fragment double buffer; loadbf(kh,pos,buf)
  const __hip_bfloat16* wBb =
      wB + (size_t)b * WB_PER_B + quad * 512 + wc * 256 + n16 * 8;
  short8 bf[2][2];
  auto loadbf = [&](int khl, int posl, int bufl) {
#pragma unroll
    for (int ntl = 0; ntl < 2; ntl++)
      bf[bufl][ntl] = *(const short8*)(wBb + (size_t)posl * 4096 + khl * 2048 +
                                       ntl * 128);
  };

  stage(0, 0);
  loadbf(0, 0, 0);                        // flies with stage-0

  float bias[2];
#pragma unroll
  for (int ntl = 0; ntl < 2; ntl++)
    bias[ntl] = bcomb[b * C_ + (wc * 2 + ntl) * 16 + n16];

  float4v acc[4][2];
#pragma unroll
  for (int mt = 0; mt < 4; mt++)
#pragma unroll
    for (int ntl = 0; ntl < 2; ntl++) acc[mt][ntl] = (float4v)0.f;

  int cur = 0;
#pragma unroll
  for (int kh = 0; kh < 2; kh++) {
    __syncthreads();                      // buffer kh staged (drains vmcnt)
    if (kh == 0) stage(1, 1);             // next half's loads fly under compute

#pragma unroll
    for (int pos = 0; pos < 9; pos++) {
      const int nxt = cur ^ 1;
      if (pos < 8) loadbf(kh, pos + 1, nxt);
      else if (kh == 0) loadbf(1, 0, nxt);  // prefetch kh=1's first pos
      const int krow = pos / 3;
      const int kw = pos - krow * 3;
      const int lr = wr + krow;           // 0..3
      short8 a[4];
#pragma unroll
      for (int mt = 0; mt < 4; mt++) {
        const int cl = mt * 16 + n16 + kw;              // 0..65
        const int slot = quad ^ (((cl + 63) >> 2) & 3); // = quad ^ ((w>>2)&3)
        a[mt] = *(const short8*)&xs[kh][((lr * COLS_T + cl) * 4 + slot) * 8];
      }
#pragma unroll
      for (int mt = 0; mt < 4; mt++)
#pragma unroll
        for (int ntl = 0; ntl < 2; ntl++)
          acc[mt][ntl] = __builtin_amdgcn_mfma_f32_16x16x32_bf16(
              a[mt], bf[cur][ntl], acc[mt][ntl], 0, 0, 0);
      cur = nxt;
    }
  }

  // ---- epilogue: full-128B-line stores via lane-pair shfl. Coltile pairs
  // (0,1) and (2,3); cx*4 is 256-B aligned so each pair covers whole lines. ----
  const int row = ty + wr;
#pragma unroll
  for (int mtp = 0; mtp < 4; mtp += 2) {
#pragma unroll
    for (int ntl = 0; ntl < 2; ntl++) {
      float4v o0 = acc[mtp][ntl];
      float4v o1 = acc[mtp + 1][ntl];
      o0.x += bias[ntl]; o0.y += bias[ntl]; o0.z += bias[ntl]; o0.w += bias[ntl];
      o1.x += bias[ntl]; o1.y += bias[ntl]; o1.z += bias[ntl]; o1.w += bias[ntl];
      const float4v vA = shx1(o1);   // even lane's o1 -> odd lane
      const float4v vB = shx1(o0);   // odd lane's o0 -> even lane
      const int odd = n16 & 1;
      const int colb = cx + (mtp + odd) * 16 + quad * 4;
      const float4v dA = odd ? vA : o0;   // even channels line
      const float4v dB = odd ? o1 : vB;   // odd channels line
      const int chA = (wc * 2 + ntl) * 16 + (n16 & ~1);
      const int chB = (wc * 2 + ntl) * 16 + (n16 | 1);
      *(float4v*)(out + ((size_t)(b * C_ + chA) * HW_ + row) * HW_ + colb) = dA;
      *(float4v*)(out + ((size_t)(b * C_ + chB) * HW_ + row) * HW_ + colb) = dB;
    }
  }
}

// ---------------------------------------------------------------------------
// K3 (fallback): f32-staging conv kernel for small workspaces.
// ---------------------------------------------------------------------------
__global__ __launch_bounds__(256, 4) void conv_kernel_f32(
    const float* __restrict__ x, const __hip_bfloat16* __restrict__ wB,
    const float* __restrict__ bcomb, float* __restrict__ out) {
  __shared__ __align__(16) short xs[XS_SHORTS];

  const int t = threadIdx.x;
  const int blk = blockIdx.x;
  const int xcd = blk & 7;
  const int idx = blk >> 3;
  const int b = xcd * 2 + (idx >> 6);
  const int strip = idx & 63;
  const int ty = strip * 2;

  const int wave = t >> 6;
  const int L = t & 63;
  const int n16 = L & 15;
  const int quad = L >> 4;

  float bias[4];
#pragma unroll
  for (int nt = 0; nt < 4; nt++) bias[nt] = bcomb[b * C_ + nt * 16 + n16];

  float4v acc[4][4];
#pragma unroll
  for (int mt = 0; mt < 4; mt++)
#pragma unroll
    for (int nt = 0; nt < 4; nt++) acc[mt][nt] = (float4v)0.f;

  for (int h = 0; h < 2; h++) {
    __syncthreads();
#pragma unroll
    for (int it = 0; it < 2; it++) {
      const int i = it * 256 + t;
      const int scq = i & 31;
      const int grp = (i >> 5) & 3;
      const int r = i >> 7;
      const int gh = ty + r - 1;
      const int ci = h * 32 + grp * 8;
      float4v v[8];
      if ((unsigned)gh < (unsigned)HW_) {
        const float* p =
            x + ((size_t)(b * C_ + ci) * HW_ + gh) * HW_ + scq * 4;
#pragma unroll
        for (int k = 0; k < 8; k++)
          v[k] = *(const float4v*)(p + (size_t)k * (HW_ * HW_));
      } else {
#pragma unroll
        for (int k = 0; k < 8; k++) v[k] = (float4v)0.f;
      }
      const int slot = grp ^ (scq & 3);
#pragma unroll
      for (int kk = 0; kk < 4; kk++) {
        const int cl = scq * 4 + kk + 1;
        short8 pk;
#pragma unroll
        for (int k = 0; k < 8; k++) {
          __hip_bfloat16 bb = __float2bfloat16(v[k][kk]);
          pk[k] = *(short*)&bb;
        }
        *(short8*)&xs[((r * COLS_LDS + cl) * 4 + slot) * 8] = pk;
      }
    }
    if (t < 32) {
      const int r = t >> 3;
      const int edge = (t >> 2) & 1;
      const int slot = t & 3;
      const int cl = edge ? 129 : 0;
      *(short8*)&xs[((r * COLS_LDS + cl) * 4 + slot) * 8] = (short8)0;
    }
    __syncthreads();

    const __hip_bfloat16* wBh =
        wB + (size_t)b * WB_PER_B + (size_t)(h * 4 + quad) * 512 + n16 * 8;
    short8 bf[2][4];
#pragma unroll
    for (int nt = 0; nt < 4; nt++)
      bf[0][nt] = *(const short8*)(wBh + nt * 128);

#pragma unroll
    for (int pos = 0; pos < 9; pos++) {
      const int cur = pos & 1;
      if (pos < 8) {
#pragma unroll
        for (int nt = 0; nt < 4; nt++)
          bf[cur ^ 1][nt] =
              *(const short8*)(wBh + (size_t)(pos + 1) * 4096 + nt * 128);
      }
      const int kh = pos / 3;
      const int kw = pos - kh * 3;
      short8 a[4];
#pragma unroll
      for (int mt = 0; mt < 4; mt++) {
        const int mtg = wave * 4 + mt;
        const int lr = (mtg >> 3) + kh;
        const int cl = (mtg & 7) * 16 + n16 + kw;
        const int slot = quad ^ (((cl - 1) >> 2) & 3);
        a[mt] = *(const short8*)&xs[((lr * COLS_LDS + cl) * 4 + slot) * 8];
      }
#pragma unroll
      for (int mt = 0; mt < 4; mt++)
#pragma unroll
        for (int nt = 0; nt < 4; nt++)
          acc[mt][nt] = __builtin_amdgcn_mfma_f32_16x16x32_bf16(
              a[mt], bf[cur][nt], acc[mt][nt], 0, 0, 0);
    }
  }

#pragma unroll
  for (int mtp = 0; mtp < 4; mtp += 2) {
#pragma unroll
    for (int nt = 0; nt < 4; nt++) {
#pragma unroll
      for (int d = 0; d < 2; d++) {
        const int mt = mtp + d;
        const int mtg = wave * 4 + mt;
        const int row = ty + (mtg >> 3);
        const int cb = (mtg & 7) * 16 + quad * 4;
        float4v o = acc[mt][nt];
        o.x += bias[nt];
        o.y += bias[nt];
        o.z += bias[nt];
        o.w += bias[nt];
        *(float4v*)(out +
                    ((size_t)(b * C_ + nt * 16 + n16) * HW_ + row) * HW_ + cb) =
            o;
      }
    }
  }
}

// ---------------------------------------------------------------------------
extern "C" void kernel_launch(void* const* d_in, const int* in_sizes, int n_in,
                              void* d_out, int out_size, void* d_ws,
                              size_t ws_size, hipStream_t stream) {
  const float* x     = (const float*)d_in[0];
  const float* wg1   = (const float*)d_in[1];
  const float* bg1   = (const float*)d_in[2];
  const float* wg2   = (const float*)d_in[3];
  const float* bg2   = (const float*)d_in[4];
  const float* w_exp = (const float*)d_in[5];
  const float* b_exp = (const float*)d_in[6];
  float* out = (float*)d_out;

  char* ws = (char*)d_ws;
  __hip_bfloat16* wB = (__hip_bfloat16*)(ws + WS_WB_OFF);
  float* bcomb = (float*)(ws + WS_BCOMB_OFF);
  float* pp    = (float*)(ws + WS_PP_OFF);

  if (ws_size >= WS_NEED) {
    __hip_bfloat16* xp = (__hip_bfloat16*)(ws + WS_XP_OFF);
    transpose_pool_kernel<<<B_ * 64, 256, 0, stream>>>(x, xp, pp);
    combine_kernel<<<B_ * 16, 256, 0, stream>>>(w_exp, nullptr, pp, 1, wg1, bg1,
                                                wg2, bg2, b_exp, wB, bcomb);
    conv_kernel_v4<<<2048, 256, 0, stream>>>(xp, wB, bcomb, out);
  } else {
    float* pooled = pp;  // 1024 floats, fits in the small-ws region
    pool_kernel<<<B_ * C_, 256, 0, stream>>>(x, pooled);
    combine_kernel<<<B_ * 16, 256, 0, stream>>>(w_exp, pooled, nullptr, 0, wg1,
                                                bg1, wg2, bg2, b_exp, wB, bcomb);
    conv_kernel_f32<<<1024, 256, 0, stream>>>(x, wB, bcomb, out);
  }
}

// Round 6
// 159.203 us; speedup vs baseline: 1.0595x; 1.0595x over previous
//
#include <hip/hip_runtime.h>
#include <hip/hip_bf16.h>
#include <math.h>

#define B_  16
#define C_  64
#define HW_ 128
#define E_  8
#define GH_ 16

typedef __attribute__((ext_vector_type(8))) short short8;
typedef __attribute__((ext_vector_type(4))) short short4v;
typedef __attribute__((ext_vector_type(4))) float float4v;

// per-sample packed weights: [9 pos][2 khalf][4 quad][64 co][8 ci] bf16
#define WB_PER_B (9 * 2 * 4 * 64 * 8)     // 36864

// ---- workspace layout (bytes) ----
#define WS_WB_OFF     0
#define WS_WB_BYTES   (B_ * WB_PER_B * 2)               // 1,179,648
#define WS_BCOMB_OFF  (WS_WB_OFF + WS_WB_BYTES)
#define WS_BCOMB_BYTES (B_ * C_ * 4)                    // 4096
#define WS_PP_OFF     (WS_BCOMB_OFF + WS_BCOMB_BYTES)
#define WS_PP_BYTES   (B_ * C_ * 64 * 4)                // 262,144 (pool partials [b][c][rb])
#define WS_XP_OFF     (WS_PP_OFF + WS_PP_BYTES)         // 16B aligned
#define WS_XP_BYTES   ((size_t)B_ * HW_ * HW_ * C_ * 2) // 33,554,432 (bf16 NHWC swizzled)
#define WS_NEED       ((size_t)WS_XP_OFF + WS_XP_BYTES)

// fallback (old conv) tiling constants
#define ROWS_LDS 4
#define COLS_LDS 132
#define XS_SHORTS (ROWS_LDS * COLS_LDS * 32)

// v4 conv LDS: [4 rows][66 cols][4 slots][8 ci] bf16 per buffer, dbuf
#define COLS_T 66
#define BUFT_SHORTS (4 * COLS_T * 32)     // 8448 shorts = 16896 B

// ---------------------------------------------------------------------------
// K1: fused transpose + pool.
// Reads x [b][c][h][w] f32; writes xp [b][h][w][64] bf16 with per-column-quad
// ci-group swizzle baked in: within each 32-ci half, group slot p at column w
// holds ci-group (p ^ ((w>>2)&3)).  Also writes per-(b,c) row-block partial
// sums pp[b][c][rb] (rb = 2-row block, 64 per image) for the gate pool.
// ---------------------------------------------------------------------------
__global__ __launch_bounds__(256) void transpose_pool_kernel(
    const float* __restrict__ x, __hip_bfloat16* __restrict__ xp,
    float* __restrict__ pp) {
  __shared__ float pred[256 * 4];
  const int t = threadIdx.x;
  const int b = blockIdx.x >> 6;
  const int rb = blockIdx.x & 63;
  const int cg = t & 15;        // channel-quad (4 ch each)
  const int cq = t >> 4;        // col-quad index within half-row
  const int g = cg >> 1;        // 8-ci group 0..7
  const int kh = g >> 2;        // ci half
  const int g_lo = g & 3;
  const int h4 = cg & 1;        // which 4 of the 8-group

  float s0 = 0.f, s1 = 0.f, s2 = 0.f, s3 = 0.f;

  for (int rr = 0; rr < 2; rr++) {
    const int r = rb * 2 + rr;
    const float* xr = x + ((size_t)b * C_ * HW_ + (size_t)r) * HW_;
    __hip_bfloat16* xpr = xp + ((size_t)(b * HW_ + r) * HW_) * C_;
#pragma unroll
    for (int ih = 0; ih < 2; ih++) {
      const int w4 = ih * 16 + cq;    // 0..31
      float4v v0 = *(const float4v*)(xr + (size_t)(cg * 4 + 0) * (HW_ * HW_) + w4 * 4);
      float4v v1 = *(const float4v*)(xr + (size_t)(cg * 4 + 1) * (HW_ * HW_) + w4 * 4);
      float4v v2 = *(const float4v*)(xr + (size_t)(cg * 4 + 2) * (HW_ * HW_) + w4 * 4);
      float4v v3 = *(const float4v*)(xr + (size_t)(cg * 4 + 3) * (HW_ * HW_) + w4 * 4);
      s0 += (v0.x + v0.y) + (v0.z + v0.w);
      s1 += (v1.x + v1.y) + (v1.z + v1.w);
      s2 += (v2.x + v2.y) + (v2.z + v2.w);
      s3 += (v3.x + v3.y) + (v3.z + v3.w);
      const int pos_lo = g_lo ^ (w4 & 3);
      const int coff = kh * 32 + pos_lo * 8 + h4 * 4;
#pragma unroll
      for (int j = 0; j < 4; j++) {
        const int w = w4 * 4 + j;
        __hip_bfloat16 b0 = __float2bfloat16(v0[j]);
        __hip_bfloat16 b1 = __float2bfloat16(v1[j]);
        __hip_bfloat16 b2 = __float2bfloat16(v2[j]);
        __hip_bfloat16 b3 = __float2bfloat16(v3[j]);
        short4v pk;
        pk[0] = *(short*)&b0;
        pk[1] = *(short*)&b1;
        pk[2] = *(short*)&b2;
        pk[3] = *(short*)&b3;
        *(short4v*)(xpr + (size_t)w * C_ + coff) = pk;
      }
    }
  }
  pred[t * 4 + 0] = s0;
  pred[t * 4 + 1] = s1;
  pred[t * 4 + 2] = s2;
  pred[t * 4 + 3] = s3;
  __syncthreads();
  if (t < C_) {
    const int kk = t & 3, cgr = t >> 2;
    float a = 0.f;
#pragma unroll
    for (int m = 0; m < 16; m++) a += pred[(cgr + 16 * m) * 4 + kk];
    pp[((size_t)b * C_ + t) * 64 + rb] = a;
  }
}

// ---------------------------------------------------------------------------
// K1 (fallback): plain global average pool.
// ---------------------------------------------------------------------------
__global__ __launch_bounds__(256) void pool_kernel(const float* __restrict__ x,
                                                   float* __restrict__ pooled) {
  const int bc = blockIdx.x;
  const float4v* p4 = (const float4v*)(x + (size_t)bc * (HW_ * HW_));
  float4v s4 = {0.f, 0.f, 0.f, 0.f};
  for (int i = threadIdx.x; i < (HW_ * HW_) / 4; i += 256) s4 += p4[i];
  float s = (s4.x + s4.y) + (s4.z + s4.w);
#pragma unroll
  for (int off = 32; off > 0; off >>= 1) s += __shfl_down(s, off, 64);
  __shared__ float red[4];
  if ((threadIdx.x & 63) == 0) red[threadIdx.x >> 6] = s;
  __syncthreads();
  if (threadIdx.x == 0)
    pooled[bc] = (red[0] + red[1] + red[2] + red[3]) * (1.0f / (HW_ * HW_));
}

// ---------------------------------------------------------------------------
// K2: fused gate + weight combine into packed bf16 B-fragment layout, with
// the residual identity folded into the center tap. block=(b, co-group of 8).
// use_pp=1: pooled means come from pp partials; else from pooled[].
// ---------------------------------------------------------------------------
__global__ __launch_bounds__(256) void combine_kernel(
    const float* __restrict__ w_exp, const float* __restrict__ pooled,
    const float* __restrict__ pp, const int use_pp,
    const float* __restrict__ wg1, const float* __restrict__ bg1,
    const float* __restrict__ wg2, const float* __restrict__ bg2,
    const float* __restrict__ b_exp, __hip_bfloat16* __restrict__ wB,
    float* __restrict__ bcomb) {
  __shared__ float wtmp[8 * 576];
  __shared__ float hsh[GH_];
  __shared__ float psh[E_];
  __shared__ float pool_sh[C_];
  const int t = threadIdx.x;
  const int b = blockIdx.x >> 3;
  const int cog = blockIdx.x & 7;

  if (use_pp) {
    if (t < C_) {
      const float4v* pr = (const float4v*)(pp + ((size_t)b * C_ + t) * 64);
      float4v s4 = {0.f, 0.f, 0.f, 0.f};
#pragma unroll
      for (int m = 0; m < 16; m++) s4 += pr[m];
      pool_sh[t] = ((s4.x + s4.y) + (s4.z + s4.w)) * (1.0f / (HW_ * HW_));
    }
  } else {
    if (t < C_) pool_sh[t] = pooled[b * C_ + t];
  }
  __syncthreads();

  if (t < GH_) {
    float s = bg1[t];
    for (int c = 0; c < C_; c++)
      s = fmaf(pool_sh[c], wg1[c * GH_ + t], s);
    hsh[t] = fmaxf(s, 0.f);
  }
  __syncthreads();
  if (t == 0) {
    float p[E_];
    float mx = -1e30f;
#pragma unroll
    for (int e = 0; e < E_; e++) {
      float s = bg2[e];
#pragma unroll
      for (int g = 0; g < GH_; g++) s = fmaf(hsh[g], wg2[g * E_ + e], s);
      p[e] = s;
      mx = fmaxf(mx, s);
    }
    float sum = 0.f;
#pragma unroll
    for (int e = 0; e < E_; e++) { p[e] = expf(p[e] - mx); sum += p[e]; }
    const float inv = 1.0f / sum;
#pragma unroll
    for (int e = 0; e < E_; e++) p[e] *= inv;
    int i1 = 0;
#pragma unroll
    for (int e = 1; e < E_; e++) if (p[e] > p[i1]) i1 = e;
    int i2 = -1;
#pragma unroll
    for (int e = 0; e < E_; e++) {
      if (e == i1) continue;
      if (i2 < 0 || p[e] > p[i2]) i2 = e;
    }
    const float denom = p[i1] + p[i2] + 1e-8f;
#pragma unroll
    for (int e = 0; e < E_; e++)
      psh[e] = (e == i1 || e == i2) ? (p[e] / denom) : 0.f;
  }
  __syncthreads();
  float pb[E_];
#pragma unroll
  for (int e = 0; e < E_; e++) pb[e] = psh[e];

  const size_t src0 = (size_t)cog * 8 * 576;
  for (int i = t; i < 4608; i += 256) {
    float s = 0.f;
#pragma unroll
    for (int e = 0; e < E_; e++)
      s = fmaf(pb[e], w_exp[(size_t)e * (C_ * 576) + src0 + i], s);
    wtmp[i] = s;
  }
  __syncthreads();
  for (int i = t; i < 4608; i += 256) {
    const int j = i & 7;
    const int co_l = (i >> 3) & 7;
    const int rest = i >> 6;
    const int quad = rest & 3;
    const int khalf = (rest >> 2) & 1;
    const int pos = rest >> 3;
    const int ci = khalf * 32 + quad * 8 + j;
    const int co = cog * 8 + co_l;
    float v = wtmp[co_l * 576 + ci * 9 + pos];
    if (pos == 4 && co == ci) v += 1.0f;   // fold residual into conv
    wB[(size_t)b * WB_PER_B +
       ((((pos * 2 + khalf) * 4 + quad) * 64) + co) * 8 + j] =
        __float2bfloat16(v);
  }
  if (t < 8) {
    const int co = cog * 8 + t;
    float s = 0.f;
#pragma unroll
    for (int e = 0; e < E_; e++) s = fmaf(pb[e], b_exp[e * C_ + co], s);
    bcomb[b * C_ + co] = s;
  }
}

__device__ __forceinline__ float4v shx1(float4v v) {
  float4v r;
  r.x = __shfl_xor(v.x, 1, 64);
  r.y = __shfl_xor(v.y, 1, 64);
  r.z = __shfl_xor(v.z, 1, 64);
  r.w = __shfl_xor(v.w, 1, 64);
  return r;
}

// ---------------------------------------------------------------------------
// K3 (v4): implicit-GEMM conv from bf16 NHWC-swizzled xp.
// Tile = 2 rows x 64 cols (M=128); grid 2048; dbuf LDS = 2 x 16,896 B =
// 33,792 B -> 4 blocks/CU WITH the round-1 double-buffered pipeline.
// Wave layout 2M x 2N (wr = row-half, wc = co-half): halves per-block wB
// redundancy so total wB L2 traffic stays at the v2 level despite 2x blocks.
// Resident window (first 1024 blocks) = one sample per XCD (round-1's
// proven 6 MB footprint; round-2's 12 MB thrashed L2).
// Interior staging: pure global_load_lds w16 (per-wave dest contiguity holds:
// lw spans one 16-col window per wave).  Edge cols (real data now): reg ->
// ds_write (global_load_lds's wave-uniform dest rule forbids them).
// ---------------------------------------------------------------------------
__global__ __launch_bounds__(256, 4) void conv_kernel_v4(
    const __hip_bfloat16* __restrict__ xp, const __hip_bfloat16* __restrict__ wB,
    const float* __restrict__ bcomb, float* __restrict__ out) {
  __shared__ __align__(16) short xs[2][BUFT_SHORTS];

  const int t = threadIdx.x;
  const int blk = blockIdx.x;
  const int xcd = blk & 7;
  const int idx = blk >> 3;               // 0..255
  const int b = xcd * 2 + (idx >> 7);
  const int tile = idx & 127;             // 64 strips x 2 col-halves
  const int ty = (tile >> 1) * 2;
  const int cx = (tile & 1) * 64;

  const int wave = t >> 6;
  const int L = t & 63;
  const int n16 = L & 15;
  const int quad = L >> 4;
  const int wr = wave >> 1;               // row-half 0..1
  const int wc = wave & 1;                // co-half 0..1

  float bias[2];
#pragma unroll
  for (int ntl = 0; ntl < 2; ntl++)
    bias[ntl] = bcomb[b * C_ + (wc * 2 + ntl) * 16 + n16];

  float4v acc[4][2];
#pragma unroll
  for (int mt = 0; mt < 4; mt++)
#pragma unroll
    for (int ntl = 0; ntl < 2; ntl++) acc[mt][ntl] = (float4v)0.f;

  // stage ci-half khs into buffer buf: 1024 interior 16-B chunks (4/thread)
  // + 32 edge chunks (reg->LDS).
  auto stage = [&](int khs, int buf) {
#pragma unroll
    for (int it = 0; it < 4; it++) {
      const int i = it * 256 + t;
      const int slot = i & 3;             // 16-B chunk within 64-B pixel-half
      const int pix = i >> 2;             // 0..255
      const int lw = pix & 63;            // local col
      const int r = pix >> 6;             // 0..3, wave-uniform
      const int gh = ty + r - 1;
      short* dst = &xs[buf][((r * COLS_T + lw + 1) * 4 + slot) * 8];
      if ((unsigned)gh < (unsigned)HW_) {
        const __hip_bfloat16* src =
            xp + ((size_t)(b * HW_ + gh) * HW_ + (cx + lw)) * C_ + khs * 32 +
            slot * 8;
        __builtin_amdgcn_global_load_lds(
            (const __attribute__((address_space(1))) void*)src,
            (__attribute__((address_space(3))) void*)dst, 16, 0, 0);
      } else {
        *(short8*)dst = (short8)0;
      }
    }
    if (t < 32) {
      const int r = t >> 3;
      const int edge = (t >> 2) & 1;
      const int slot = t & 3;
      const int cl = edge ? (COLS_T - 1) : 0;
      const int w = cx + (edge ? 64 : -1);
      const int gh = ty + r - 1;
      short8 v = (short8)0;
      if ((unsigned)gh < (unsigned)HW_ && (unsigned)w < (unsigned)HW_)
        v = *(const short8*)(xp + ((size_t)(b * HW_ + gh) * HW_ + w) * C_ +
                             khs * 32 + slot * 8);
      *(short8*)&xs[buf][((r * COLS_T + cl) * 4 + slot) * 8] = v;
    }
  };

  stage(0, 0);

#pragma unroll
  for (int kh = 0; kh < 2; kh++) {
    __syncthreads();                      // buffer kh staged (drains vmcnt)
    if (kh == 0) stage(1, 1);             // next half's loads fly under compute

    const __hip_bfloat16* wBh = wB + (size_t)b * WB_PER_B +
                                (size_t)(kh * 4 + quad) * 512 + wc * 256 +
                                n16 * 8;
    short8 bf[2][2];
#pragma unroll
    for (int ntl = 0; ntl < 2; ntl++)
      bf[0][ntl] = *(const short8*)(wBh + ntl * 128);

#pragma unroll
    for (int pos = 0; pos < 9; pos++) {
      const int cur = pos & 1;
      if (pos < 8) {
#pragma unroll
        for (int ntl = 0; ntl < 2; ntl++)
          bf[cur ^ 1][ntl] =
              *(const short8*)(wBh + (size_t)(pos + 1) * 4096 + ntl * 128);
      }
      const int krow = pos / 3;
      const int kw = pos - krow * 3;
      const int lr = wr + krow;           // 0..3
      short8 a[4];
#pragma unroll
      for (int mt = 0; mt < 4; mt++) {
        const int cl = mt * 16 + n16 + kw;              // 0..65
        const int slot = quad ^ (((cl + 63) >> 2) & 3); // = quad ^ ((w>>2)&3)
        a[mt] = *(const short8*)&xs[kh][((lr * COLS_T + cl) * 4 + slot) * 8];
      }
#pragma unroll
      for (int mt = 0; mt < 4; mt++)
#pragma unroll
        for (int ntl = 0; ntl < 2; ntl++)
          acc[mt][ntl] = __builtin_amdgcn_mfma_f32_16x16x32_bf16(
              a[mt], bf[cur][ntl], acc[mt][ntl], 0, 0, 0);
    }
  }

  // ---- epilogue: full-128B-line stores via lane-pair shfl. Coltile pairs
  // (0,1) and (2,3); cx*4 is 256-B aligned so each pair covers whole lines. ----
  const int row = ty + wr;
#pragma unroll
  for (int mtp = 0; mtp < 4; mtp += 2) {
#pragma unroll
    for (int ntl = 0; ntl < 2; ntl++) {
      float4v o0 = acc[mtp][ntl];
      float4v o1 = acc[mtp + 1][ntl];
      o0.x += bias[ntl]; o0.y += bias[ntl]; o0.z += bias[ntl]; o0.w += bias[ntl];
      o1.x += bias[ntl]; o1.y += bias[ntl]; o1.z += bias[ntl]; o1.w += bias[ntl];
      const float4v vA = shx1(o1);   // even lane's o1 -> odd lane
      const float4v vB = shx1(o0);   // odd lane's o0 -> even lane
      const int odd = n16 & 1;
      const int colb = cx + (mtp + odd) * 16 + quad * 4;
      const float4v dA = odd ? vA : o0;   // even channels line
      const float4v dB = odd ? o1 : vB;   // odd channels line
      const int chA = (wc * 2 + ntl) * 16 + (n16 & ~1);
      const int chB = (wc * 2 + ntl) * 16 + (n16 | 1);
      *(float4v*)(out + ((size_t)(b * C_ + chA) * HW_ + row) * HW_ + colb) = dA;
      *(float4v*)(out + ((size_t)(b * C_ + chB) * HW_ + row) * HW_ + colb) = dB;
    }
  }
}

// ---------------------------------------------------------------------------
// K3 (fallback): f32-staging conv kernel for small workspaces.
// ---------------------------------------------------------------------------
__global__ __launch_bounds__(256, 4) void conv_kernel_f32(
    const float* __restrict__ x, const __hip_bfloat16* __restrict__ wB,
    const float* __restrict__ bcomb, float* __restrict__ out) {
  __shared__ __align__(16) short xs[XS_SHORTS];

  const int t = threadIdx.x;
  const int blk = blockIdx.x;
  const int xcd = blk & 7;
  const int idx = blk >> 3;
  const int b = xcd * 2 + (idx >> 6);
  const int strip = idx & 63;
  const int ty = strip * 2;

  const int wave = t >> 6;
  const int L = t & 63;
  const int n16 = L & 15;
  const int quad = L >> 4;

  float bias[4];
#pragma unroll
  for (int nt = 0; nt < 4; nt++) bias[nt] = bcomb[b * C_ + nt * 16 + n16];

  float4v acc[4][4];
#pragma unroll
  for (int mt = 0; mt < 4; mt++)
#pragma unroll
    for (int nt = 0; nt < 4; nt++) acc[mt][nt] = (float4v)0.f;

  for (int h = 0; h < 2; h++) {
    __syncthreads();
#pragma unroll
    for (int it = 0; it < 2; it++) {
      const int i = it * 256 + t;
      const int scq = i & 31;
      const int grp = (i >> 5) & 3;
      const int r = i >> 7;
      const int gh = ty + r - 1;
      const int ci = h * 32 + grp * 8;
      float4v v[8];
      if ((unsigned)gh < (unsigned)HW_) {
        const float* p =
            x + ((size_t)(b * C_ + ci) * HW_ + gh) * HW_ + scq * 4;
#pragma unroll
        for (int k = 0; k < 8; k++)
          v[k] = *(const float4v*)(p + (size_t)k * (HW_ * HW_));
      } else {
#pragma unroll
        for (int k = 0; k < 8; k++) v[k] = (float4v)0.f;
      }
      const int slot = grp ^ (scq & 3);
#pragma unroll
      for (int kk = 0; kk < 4; kk++) {
        const int cl = scq * 4 + kk + 1;
        short8 pk;
#pragma unroll
        for (int k = 0; k < 8; k++) {
          __hip_bfloat16 bb = __float2bfloat16(v[k][kk]);
          pk[k] = *(short*)&bb;
        }
        *(short8*)&xs[((r * COLS_LDS + cl) * 4 + slot) * 8] = pk;
      }
    }
    if (t < 32) {
      const int r = t >> 3;
      const int edge = (t >> 2) & 1;
      const int slot = t & 3;
      const int cl = edge ? 129 : 0;
      *(short8*)&xs[((r * COLS_LDS + cl) * 4 + slot) * 8] = (short8)0;
    }
    __syncthreads();

    const __hip_bfloat16* wBh =
        wB + (size_t)b * WB_PER_B + (size_t)(h * 4 + quad) * 512 + n16 * 8;
    short8 bf[2][4];
#pragma unroll
    for (int nt = 0; nt < 4; nt++)
      bf[0][nt] = *(const short8*)(wBh + nt * 128);

#pragma unroll
    for (int pos = 0; pos < 9; pos++) {
      const int cur = pos & 1;
      if (pos < 8) {
#pragma unroll
        for (int nt = 0; nt < 4; nt++)
          bf[cur ^ 1][nt] =
              *(const short8*)(wBh + (size_t)(pos + 1) * 4096 + nt * 128);
      }
      const int kh = pos / 3;
      const int kw = pos - kh * 3;
      short8 a[4];
#pragma unroll
      for (int mt = 0; mt < 4; mt++) {
        const int mtg = wave * 4 + mt;
        const int lr = (mtg >> 3) + kh;
        const int cl = (mtg & 7) * 16 + n16 + kw;
        const int slot = quad ^ (((cl - 1) >> 2) & 3);
        a[mt] = *(const short8*)&xs[((lr * COLS_LDS + cl) * 4 + slot) * 8];
      }
#pragma unroll
      for (int mt = 0; mt < 4; mt++)
#pragma unroll
        for (int nt = 0; nt < 4; nt++)
          acc[mt][nt] = __builtin_amdgcn_mfma_f32_16x16x32_bf16(
              a[mt], bf[cur][nt], acc[mt][nt], 0, 0, 0);
    }
  }

#pragma unroll
  for (int mtp = 0; mtp < 4; mtp += 2) {
#pragma unroll
    for (int nt = 0; nt < 4; nt++) {
#pragma unroll
      for (int d = 0; d < 2; d++) {
        const int mt = mtp + d;
        const int mtg = wave * 4 + mt;
        const int row = ty + (mtg >> 3);
        const int cb = (mtg & 7) * 16 + quad * 4;
        float4v o = acc[mt][nt];
        o.x += bias[nt];
        o.y += bias[nt];
        o.z += bias[nt];
        o.w += bias[nt];
        *(float4v*)(out +
                    ((size_t)(b * C_ + nt * 16 + n16) * HW_ + row) * HW_ + cb) =
            o;
      }
    }
  }
}

// ---------------------------------------------------------------------------
extern "C" void kernel_launch(void* const* d_in, const int* in_sizes, int n_in,
                              void* d_out, int out_size, void* d_ws,
                              size_t ws_size, hipStream_t stream) {
  const float* x     = (const float*)d_in[0];
  const float* wg1   = (const float*)d_in[1];
  const float* bg1   = (const float*)d_in[2];
  const float* wg2   = (const float*)d_in[3];
  const float* bg2   = (const float*)d_in[4];
  const float* w_exp = (const float*)d_in[5];
  const float* b_exp = (const float*)d_in[6];
  float* out = (float*)d_out;

  char* ws = (char*)d_ws;
  __hip_bfloat16* wB = (__hip_bfloat16*)(ws + WS_WB_OFF);
  float* bcomb = (float*)(ws + WS_BCOMB_OFF);
  float* pp    = (float*)(ws + WS_PP_OFF);

  if (ws_size >= WS_NEED) {
    __hip_bfloat16* xp = (__hip_bfloat16*)(ws + WS_XP_OFF);
    transpose_pool_kernel<<<B_ * 64, 256, 0, stream>>>(x, xp, pp);
    combine_kernel<<<B_ * 8, 256, 0, stream>>>(w_exp, nullptr, pp, 1, wg1, bg1,
                                               wg2, bg2, b_exp, wB, bcomb);
    conv_kernel_v4<<<2048, 256, 0, stream>>>(xp, wB, bcomb, out);
  } else {
    float* pooled = pp;  // 1024 floats, fits in the small-ws region
    pool_kernel<<<B_ * C_, 256, 0, stream>>>(x, pooled);
    combine_kernel<<<B_ * 8, 256, 0, stream>>>(w_exp, pooled, nullptr, 0, wg1,
                                               bg1, wg2, bg2, b_exp, wB, bcomb);
    conv_kernel_f32<<<1024, 256, 0, stream>>>(x, wB, bcomb, out);
  }
}